// Round 10
// baseline (300.613 us; speedup 1.0000x reference)
//
#include <hip/hip_runtime.h>
#include <math.h>

// Model dims
#define BB 8
#define TT 150
#define DD 30
#define HH 5
#define HD 6
#define LL 3
#define NI 40            // B*H heads per stream
#define ROWF (TT*BB*DD)  // 36000 floats per [T,B,D] buffer
#define RSTR 8           // padded LDS row stride in halves (16B -> ds_read_b128)
#define NR 152           // padded row count (150 data + vbar + zero)

typedef _Float16 half8 __attribute__((ext_vector_type(8)));
typedef float f32x16 __attribute__((ext_vector_type(16)));

__device__ __forceinline__ float wsum(float v) {
    #pragma unroll
    for (int m = 32; m > 0; m >>= 1) v += __shfl_xor(v, m, 64);
    return v;
}

// Fused pre-pass. Blocks [0,1800): k,v for all 6 (s,l) — pa/pv rows recomputed
// inline from x_a/x_v (cheap) so no dependency on a projection kernel.
// Blocks [1800,2400): pl rows from x_l (written to global for the l=0 residual)
// + LN + q-projection for layer 0. Also zeroes the head counter.
__global__ __launch_bounds__(256) void fused_pre_kernel(
    const float* __restrict__ x_l, const float* __restrict__ x_a, const float* __restrict__ x_v,
    const float* __restrict__ Wl, const float* __restrict__ Wa, const float* __restrict__ Wv,
    const float* __restrict__ in_w, const float* __restrict__ in_b,
    const float* __restrict__ n1g, const float* __restrict__ n1b,
    float* __restrict__ pl, float* __restrict__ k_all, float* __restrict__ v_all,
    float* __restrict__ q, int* __restrict__ counter) {
    __shared__ float sm[11264];
    int blk = blockIdx.x;                   // [0,2400)
    int tid = threadIdx.x;
    int w = tid >> 6, lane = tid & 63;
    if (blk == 0 && tid == 0) *counter = 0;

    if (blk < 1800) {
        float* WaS = sm;            // 2220  (30 x 74)
        float* WvS = sm + 2220;     // 1050  (30 x 35)
        float* iwS = sm + 3270;     // 1800  (k,v rows 30..89)
        float* xaR = sm + 5070;     // 4 x 80
        float* xvR = sm + 5390;     // 4 x 40
        float* xn  = sm + 5550;     // 4 x 64 (two 32-slot LN vectors per wave)
        int po = blk / 300;         // s*LL+l
        int s = po / LL;
        int tb = (blk % 300) * 4 + w;
        int t = tb / BB, b = tb % BB;
        for (int j = tid; j < 2220; j += 256) WaS[j] = Wa[j];
        for (int j = tid; j < 1050; j += 256) WvS[j] = Wv[j];
        const float* iw = in_w + (size_t)po * 2700 + 900;
        for (int j = tid; j < 1800; j += 256) iwS[j] = iw[j];
        const float* xa = x_a + ((size_t)b * TT + t) * 74;
        const float* xv = x_v + ((size_t)b * TT + t) * 35;
        for (int j = lane; j < 74; j += 64) xaR[w * 80 + j] = xa[j];
        if (lane < 35) xvR[w * 40 + lane] = xv[lane];
        __syncthreads();
        float pav = 0.f, pvv = 0.f;
        if (lane < 30) {
            const float* wr = WaS + lane * 74;
            #pragma unroll 2
            for (int j = 0; j < 74; j++) pav += wr[j] * xaR[w * 80 + j];
            const float* wr2 = WvS + lane * 35;
            #pragma unroll 5
            for (int j = 0; j < 35; j++) pvv += wr2[j] * xvR[w * 40 + j];
        }
        const float* g  = n1g + (size_t)po * 30;
        const float* bb = n1b + (size_t)po * 30;
        const float* ib = in_b + (size_t)po * 90;
        float r01[2];
        r01[0] = (s == 0) ? pav : pvv;   // k-source
        r01[1] = (s == 0) ? pvv : pav;   // v-source
        #pragma unroll
        for (int r = 0; r < 2; r++) {
            float xval = (lane < 30) ? r01[r] : 0.f;
            float mean = wsum(xval) * (1.f / 30.f);
            float dv = (lane < 30) ? (xval - mean) : 0.f;
            float var = wsum(dv * dv) * (1.f / 30.f);
            float inv = rsqrtf(var + 1e-5f);
            if (lane < 30) xn[w * 64 + r * 32 + lane] = dv * inv * g[lane] + bb[lane];
        }
        // xn written/read within the same wave; iwS barrier already done above
        if (lane < 60) {
            int which = lane / 30, dd = lane % 30;
            const float* wr = iwS + lane * 30;
            const float* xr = xn + w * 64 + which * 32;
            float acc = 0.f;
            #pragma unroll 6
            for (int j = 0; j < 30; j++) acc += wr[j] * xr[j];
            acc += ib[30 + lane];
            int i = b * HH + dd / HD, hd = dd % HD;
            float* dst = which ? v_all : k_all;
            dst[((size_t)po * NI + i) * (TT * HD) + t * HD + hd] = acc;
        }
    } else {
        float* WlS = sm;            // 9000 (30 x 300)
        float* iwq = sm + 9000;     // 900  (q rows 0..29)
        float* xlR = sm + 9900;     // 4 x 304 (x_l row; later reused for xn)
        float* plR = sm + 11116;    // 4 x 32
        int r2 = blk - 1800;        // [0,600)
        int s = r2 / 300;
        int tb = (r2 % 300) * 4 + w;
        int t = tb / BB, b = tb % BB;
        int po = s * LL;            // layer 0
        for (int j = tid; j < 9000; j += 256) WlS[j] = Wl[j];
        const float* iw = in_w + (size_t)po * 2700;
        for (int j = tid; j < 900; j += 256) iwq[j] = iw[j];
        const float* xl = x_l + ((size_t)b * TT + t) * 300;
        for (int j = lane; j < 300; j += 64) xlR[w * 304 + j] = xl[j];
        __syncthreads();
        int d = lane >> 1, jh = lane & 1;
        const float* wr = WlS + (size_t)(d < DD ? d : 0) * 300;
        int j0 = jh ? 150 : 0, j1 = jh ? 300 : 150;
        float acc = 0.f;
        for (int j = j0; j < j1; j++) acc += xlR[w * 304 + j] * wr[j];
        acc += __shfl_xor(acc, 1, 64);
        if (jh == 0 && d < DD) {
            plR[w * 32 + d] = acc;
            pl[tb * 30 + d] = acc;
        }
        // LN + q-projection (wave-local LDS reuse; same-wave write->read ordering)
        float xval = (lane < 30) ? plR[w * 32 + lane] : 0.f;
        float mean = wsum(xval) * (1.f / 30.f);
        float dv = (lane < 30) ? (xval - mean) : 0.f;
        float var = wsum(dv * dv) * (1.f / 30.f);
        float inv = rsqrtf(var + 1e-5f);
        const float* g  = n1g + (size_t)po * 30;
        const float* bb = n1b + (size_t)po * 30;
        const float* ib = in_b + (size_t)po * 90;
        if (lane < 30) xlR[w * 304 + lane] = dv * inv * g[lane] + bb[lane];
        if (lane < 30) {
            const float* wrq = iwq + lane * 30;
            float acc2 = 0.f;
            #pragma unroll 6
            for (int j = 0; j < 30; j++) acc2 += wrq[j] * xlR[w * 304 + j];
            acc2 = (acc2 + ib[lane]) * 0.40824829046386307f;   // HD^-0.5
            int i = b * HH + lane / HD, hd = lane % HD;
            q[((size_t)s * NI + i) * (TT * HD) + t * HD + hd] = acc2;
        }
    }
}

// Score kernel: block = (s, head i, g); stages ONE head f16 in LDS (7.3 KB),
// 4 waves x 2 a's. Fused scores via mfma_f32_32x32x16_f16; vbar row c=150
// provides the mean for free; softmax; attn = sum_b p*q -> global.
// C/D layout: col = lane&31, row = (reg&3) + 8*(reg>>2) + 4*(lane>>5).
__global__ __launch_bounds__(256) void score_kernel(
    const float* __restrict__ q, const float* __restrict__ k_all,
    const float* __restrict__ v_all, int l, float* __restrict__ attn) {
    int blk = blockIdx.x;                   // [0, 1520)
    int s = blk / 760;
    int rem = blk % 760;
    int i = rem / 19;
    int g = rem % 19;
    int tid = threadIdx.x;
    int wv = tid >> 6, lane = tid & 63;
    int lo = lane & 31, hf = lane >> 5;
    int po = s * LL + l;

    __shared__ __align__(16) _Float16 qsh[NR * RSTR];
    __shared__ __align__(16) _Float16 ksh[NR * RSTR];
    __shared__ __align__(16) _Float16 vsh[NR * RSTR];

    const float* qg = q + (size_t)(s * NI + i) * (TT * HD);
    const float* kg = k_all + (size_t)(po * NI + i) * (TT * HD);
    const float* vg = v_all + (size_t)(po * NI + i) * (TT * HD);
    half8 z8;
    #pragma unroll
    for (int t = 0; t < 8; t++) z8[t] = (_Float16)0.f;
    for (int r = tid; r < NR; r += 256) {
        half8 qa = z8, ka = z8, va = z8;
        if (r < TT) {
            #pragma unroll
            for (int t = 0; t < 6; t++) {
                qa[t] = (_Float16)qg[r * 6 + t];
                ka[t] = (_Float16)kg[r * 6 + t];
                va[t] = (_Float16)vg[r * 6 + t];
            }
        }
        *(half8*)&qsh[r * RSTR] = qa;
        *(half8*)&ksh[r * RSTR] = ka;
        *(half8*)&vsh[r * RSTR] = va;
    }
    __syncthreads();
    if (wv == 0) {   // vbar row (pre-scaled by 1/150) into vsh row 150
        float v6[6] = {0.f, 0.f, 0.f, 0.f, 0.f, 0.f};
        for (int c = lane; c < TT; c += 64) {
            #pragma unroll
            for (int t = 0; t < 6; t++) v6[t] += (float)vsh[c * RSTR + t];
        }
        #pragma unroll
        for (int m = 32; m > 0; m >>= 1) {
            #pragma unroll
            for (int t = 0; t < 6; t++) v6[t] += __shfl_xor(v6[t], m, 64);
        }
        if (lane < 6) vsh[TT * RSTR + lane] = (_Float16)(v6[lane] * (1.f / TT));
    }
    __syncthreads();

    f32x16 zacc;
    #pragma unroll
    for (int j = 0; j < 16; j++) zacc[j] = 0.f;

    half8 bfrag[5], vhalf[5];
    #pragma unroll
    for (int nt = 0; nt < 5; nt++) {
        int rr = nt * 32 + lo;
        int rc = rr < 151 ? rr : 151;          // 150 = vbar, 151 = zeros
        half8 kf = *(const half8*)&ksh[rc * RSTR];
        half8 vf = *(const half8*)&vsh[rc * RSTR];
        bfrag[nt] = hf ? z8 : kf;
        vhalf[nt] = hf ? z8 : vf;
    }

    for (int ap = 0; ap < 2; ap++) {
        int a = g * 8 + wv * 2 + ap;
        if (a >= TT) break;
        half8 qav = *(const half8*)&qsh[a * RSTR];
        half8 afrag[5];
        #pragma unroll
        for (int nt = 0; nt < 5; nt++) afrag[nt] = vhalf[nt] * qav;  // v_pk_mul_f16

        float fsc[5];
        #pragma unroll
        for (int nb = 0; nb < 5; nb++) {
            float rm = -INFINITY;
            #pragma unroll
            for (int ma = 0; ma < 4; ma++) {
                f32x16 acc = __builtin_amdgcn_mfma_f32_32x32x16_f16(afrag[ma], bfrag[nb], zacc, 0, 0, 0);
                float m = fmaxf(acc[0], acc[1]);
                #pragma unroll
                for (int j = 2; j < 16; j += 2) m = fmaxf(fmaxf(m, acc[j]), acc[j + 1]);
                rm = fmaxf(rm, m);
            }
            f32x16 a4 = __builtin_amdgcn_mfma_f32_32x32x16_f16(afrag[4], bfrag[nb], zacc, 0, 0, 0);
            // live rows: hf==0 -> regs 0..11 (c<=147); hf==1 -> regs 0..9 (c<=149)
            float m4 = fmaxf(a4[0], a4[1]);
            #pragma unroll
            for (int j = 2; j < 10; j += 2) m4 = fmaxf(fmaxf(m4, a4[j]), a4[j + 1]);
            float ext = (hf == 0) ? fmaxf(a4[10], a4[11]) : -INFINITY;
            rm = fmaxf(rm, fmaxf(m4, ext));
            // mean sits at reg10 of hf==1 lanes (row c==150 = vbar row)
            float om = __shfl_xor(a4[10], 32, 64);
            float mn = hf ? a4[10] : om;
            rm = fmaxf(rm, __shfl_xor(rm, 32, 64));
            int bcol = nb * 32 + lo;
            fsc[nb] = (bcol < TT) ? (mn + rm) : -INFINITY;
        }
        float m = fsc[0];
        #pragma unroll
        for (int nb = 1; nb < 5; nb++) m = fmaxf(m, fsc[nb]);
        #pragma unroll
        for (int msk = 16; msk > 0; msk >>= 1) m = fmaxf(m, __shfl_xor(m, msk, 64));
        float e[5], es = 0.f;
        #pragma unroll
        for (int nb = 0; nb < 5; nb++) { e[nb] = __expf(fsc[nb] - m); es += e[nb]; }
        #pragma unroll
        for (int msk = 16; msk > 0; msk >>= 1) es += __shfl_xor(es, msk, 64);
        float acc6[6] = {0.f, 0.f, 0.f, 0.f, 0.f, 0.f};
        #pragma unroll
        for (int nb = 0; nb < 5; nb++) {
            int bcol = nb * 32 + lo;
            int bi = (bcol < TT) ? bcol : 0;
            float wgt = e[nb];
            half8 qrow = *(const half8*)&qsh[bi * RSTR];
            #pragma unroll
            for (int t = 0; t < 6; t++) acc6[t] += wgt * (float)qrow[t];
        }
        #pragma unroll
        for (int msk = 16; msk > 0; msk >>= 1) {
            #pragma unroll
            for (int t = 0; t < 6; t++) acc6[t] += __shfl_xor(acc6[t], msk, 64);
        }
        if (lane == 0) {
            float inv = 1.f / es;
            int bo = i / HH, ho = i % HH;
            float* dst = attn + (size_t)s * ROWF + a * (BB * DD) + bo * DD + ho * HD;
            #pragma unroll
            for (int t = 0; t < 6; t++) dst[t] = acc6[t] * inv;
        }
    }
}

// FFN for layer l + q-projection for layer l+1. For l==2, the LAST block to
// finish (device-scope atomic counter) also runs the output head.
__global__ __launch_bounds__(256) void ffnlnq_kernel(
    const float* __restrict__ attn, const float* __restrict__ pl,
    const float* __restrict__ out_w, const float* __restrict__ out_b,
    const float* __restrict__ l1w, const float* __restrict__ l1b,
    const float* __restrict__ l2w, const float* __restrict__ l2b,
    const float* __restrict__ n2g, const float* __restrict__ n2b,
    const float* __restrict__ in_w, const float* __restrict__ in_b,
    const float* __restrict__ n1g, const float* __restrict__ n1b,
    const float* __restrict__ p1w, const float* __restrict__ p1b,
    const float* __restrict__ p2w, const float* __restrict__ p2b,
    const float* __restrict__ oww, const float* __restrict__ obb,
    int l, int has_next,
    float* __restrict__ h, float* __restrict__ q,
    int* __restrict__ counter, float* __restrict__ out) {
    int blk = blockIdx.x;                   // [0,600)
    int s = blk / 300;
    int tid = threadIdx.x;
    int w = tid >> 6, lane = tid & 63;
    int tb = (blk % 300) * 4 + w;           // [0,1200)
    int t = tb / BB, b = tb % BB;
    int po = s * LL + l;
    const float* ow = out_w + (size_t)po * 900;
    const float* ob = out_b + (size_t)po * 30;
    const float* w1 = l1w + (size_t)po * 3600;
    const float* b1 = l1b + (size_t)po * 120;
    const float* w2 = l2w + (size_t)po * 3600;
    const float* b2 = l2b + (size_t)po * 30;
    const float* g2 = n2g + (size_t)po * 30;
    const float* bb2 = n2b + (size_t)po * 30;
    __shared__ float owS[900];
    __shared__ float w1T[30 * 128];
    __shared__ float w2S[30 * 121];
    __shared__ float iwqS[900];
    __shared__ float arS[4][30], xnS[4][32], hidS[4][120], xqS[4][30];
    __shared__ float headS[1440];
    __shared__ int isLast;
    for (int j = tid; j < 900; j += 256) owS[j] = ow[j];
    for (int j = tid; j < 3600; j += 256) w1T[(j % 30) * 128 + (j / 30)] = w1[j];
    for (int j = tid; j < 3600; j += 256) w2S[(j / 120) * 121 + (j % 120)] = w2[j];
    if (has_next) {
        const float* iwq = in_w + (size_t)(po + 1) * 2700;
        for (int j = tid; j < 900; j += 256) iwqS[j] = iwq[j];
    }
    __syncthreads();
    float* hrow = h + (size_t)s * ROWF + (size_t)tb * 30;
    const float* res = (l == 0) ? (pl + (size_t)tb * 30) : hrow;
    const float* arow = attn + (size_t)s * ROWF + (size_t)tb * 30;
    if (lane < 30) arS[w][lane] = arow[lane];
    float x1v = 0.f;
    if (lane < 30) {
        const float* wr = owS + lane * 30;
        float acc = 0.f;
        #pragma unroll 6
        for (int j = 0; j < 30; j++) acc += wr[j] * arS[w][j];
        x1v = res[lane] + acc + ob[lane];
    }
    float mean = wsum(x1v) * (1.f / 30.f);
    float dv = (lane < 30) ? (x1v - mean) : 0.f;
    float var = wsum(dv * dv) * (1.f / 30.f);
    float inv = rsqrtf(var + 1e-5f);
    if (lane < 30) xnS[w][lane] = dv * inv * g2[lane] + bb2[lane];
    for (int o = lane; o < 120; o += 64) {
        float acc = 0.f;
        #pragma unroll 6
        for (int j = 0; j < 30; j++) acc += w1T[j * 128 + o] * xnS[w][j];
        hidS[w][o] = fmaxf(acc + b1[o], 0.f);
    }
    float newh = 0.f;
    if (lane < 30) {
        const float* wr = w2S + lane * 121;
        float acc = 0.f;
        #pragma unroll 8
        for (int j = 0; j < 120; j++) acc += wr[j] * hidS[w][j];
        newh = x1v + acc + b2[lane];
        hrow[lane] = newh;
    }
    if (has_next) {
        const float* g1 = n1g + (size_t)(po + 1) * 30;
        const float* bb1 = n1b + (size_t)(po + 1) * 30;
        const float* ibq = in_b + (size_t)(po + 1) * 90;
        float mean2 = wsum(newh) * (1.f / 30.f);
        float dv2 = (lane < 30) ? (newh - mean2) : 0.f;
        float var2 = wsum(dv2 * dv2) * (1.f / 30.f);
        float inv2 = rsqrtf(var2 + 1e-5f);
        if (lane < 30) xqS[w][lane] = dv2 * inv2 * g1[lane] + bb1[lane];
        if (lane < 30) {
            const float* wr = iwqS + lane * 30;
            float acc = 0.f;
            #pragma unroll 6
            for (int j = 0; j < 30; j++) acc += wr[j] * xqS[w][j];
            acc = (acc + ibq[lane]) * 0.40824829046386307f;
            int i = b * HH + lane / HD, hd = lane % HD;
            q[((size_t)s * NI + i) * (TT * HD) + t * HD + hd] = acc;
        }
    }

    if (l == 2) {
        // last-block-does-head: release fence per thread, then count blocks
        __threadfence();
        __syncthreads();
        if (tid == 0) {
            int old = atomicAdd(counter, 1);
            isLast = (old == 599);
        }
        __syncthreads();
        if (isLast) {
            __threadfence();   // acquire: make all blocks' h writes visible
            float* lh  = headS;
            float* hid = headS + 480;
            float* pr  = headS + 960;
            for (int idx = tid; idx < 480; idx += 256) {
                int b2i = idx / 60, j = idx % 60;
                int s2 = j / 30, d = j % 30;
                float vv = h[(size_t)s2 * ROWF + 149 * (BB * DD) + b2i * DD + d];
                lh[idx] = vv;
                out[8 + idx] = vv;   // last_hs
            }
            __syncthreads();
            for (int idx = tid; idx < 480; idx += 256) {
                int b2i = idx / 60, o = idx % 60;
                const float* wr = p1w + o * 60;
                float acc = p1b[o];
                for (int j = 0; j < 60; j++) acc += wr[j] * lh[b2i * 60 + j];
                hid[idx] = fmaxf(acc, 0.f);
            }
            __syncthreads();
            for (int idx = tid; idx < 480; idx += 256) {
                int b2i = idx / 60, d = idx % 60;
                const float* wr = p2w + d * 60;
                float acc = p2b[d];
                for (int j = 0; j < 60; j++) acc += wr[j] * hid[b2i * 60 + j];
                pr[idx] = acc + lh[idx];
            }
            __syncthreads();
            if (tid < 8) {
                float acc = obb[0];
                for (int j = 0; j < 60; j++) acc += pr[tid * 60 + j] * oww[j];
                out[tid] = acc;      // out
            }
        }
    }
}

extern "C" void kernel_launch(void* const* d_in, const int* in_sizes, int n_in,
                              void* d_out, int out_size, void* d_ws, size_t ws_size,
                              hipStream_t stream) {
    const float* x_l   = (const float*)d_in[0];
    const float* x_a   = (const float*)d_in[1];
    const float* x_v   = (const float*)d_in[2];
    const float* Wl    = (const float*)d_in[3];
    const float* Wa    = (const float*)d_in[4];
    const float* Wv    = (const float*)d_in[5];
    const float* in_w  = (const float*)d_in[6];
    const float* in_b  = (const float*)d_in[7];
    const float* out_w = (const float*)d_in[8];
    const float* out_b = (const float*)d_in[9];
    const float* l1w   = (const float*)d_in[10];
    const float* l1b   = (const float*)d_in[11];
    const float* l2w   = (const float*)d_in[12];
    const float* l2b   = (const float*)d_in[13];
    const float* n1g   = (const float*)d_in[14];
    const float* n1b   = (const float*)d_in[15];
    const float* n2g   = (const float*)d_in[16];
    const float* n2b   = (const float*)d_in[17];
    const float* p1w   = (const float*)d_in[18];
    const float* p1b   = (const float*)d_in[19];
    const float* p2w   = (const float*)d_in[20];
    const float* p2b   = (const float*)d_in[21];
    const float* oww   = (const float*)d_in[22];
    const float* obb   = (const float*)d_in[23];

    float* ws = (float*)d_ws;
    float* pl    = ws;             // 36000
    float* h     = ws + 108000;    // 72000  [2][T][B][D]
    float* q     = ws + 180000;    // 72000  [2][NI][TT][HD]
    float* k_all = ws + 252000;    // 216000 [6][NI][TT][HD]
    float* v_all = ws + 468000;    // 216000
    float* at    = ws + 684000;    // 72000
    int*   cnt   = (int*)(ws + 756000);

    fused_pre_kernel<<<2400, 256, 0, stream>>>(x_l, x_a, x_v, Wl, Wa, Wv,
                                               in_w, in_b, n1g, n1b,
                                               pl, k_all, v_all, q, cnt);
    for (int l = 0; l < LL; l++) {
        score_kernel<<<1520, 256, 0, stream>>>(q, k_all, v_all, l, at);
        ffnlnq_kernel<<<600, 256, 0, stream>>>(at, pl, out_w, out_b, l1w, l1b, l2w, l2b,
                                               n2g, n2b, in_w, in_b, n1g, n1b,
                                               p1w, p1b, p2w, p2b, oww, obb,
                                               l, (l < LL - 1) ? 1 : 0, h, q,
                                               cnt, (float*)d_out);
    }
}

// Round 11
// 263.823 us; speedup vs baseline: 1.1394x; 1.1394x over previous
//
#include <hip/hip_runtime.h>
#include <math.h>

// Model dims
#define BB 8
#define TT 150
#define DD 30
#define HH 5
#define HD 6
#define LL 3
#define NI 40            // B*H heads per stream
#define ROWF (TT*BB*DD)  // 36000 floats per [T,B,D] buffer
#define RSTR 8           // padded LDS row stride in halves (16B -> ds_read_b128)
#define NR 152           // padded row count (150 data + vbar + zero)

typedef _Float16 half8 __attribute__((ext_vector_type(8)));
typedef float f32x16 __attribute__((ext_vector_type(16)));

__device__ __forceinline__ float wsum(float v) {
    #pragma unroll
    for (int m = 32; m > 0; m >>= 1) v += __shfl_xor(v, m, 64);
    return v;
}

// Fused pre-pass. Blocks [0,1800): k,v for all 6 (s,l) — pa/pv rows recomputed
// inline from x_a/x_v. Blocks [1800,2400): pl rows from x_l (written for the
// l=0 residual) + LN + q-projection for layer 0.
__global__ __launch_bounds__(256) void fused_pre_kernel(
    const float* __restrict__ x_l, const float* __restrict__ x_a, const float* __restrict__ x_v,
    const float* __restrict__ Wl, const float* __restrict__ Wa, const float* __restrict__ Wv,
    const float* __restrict__ in_w, const float* __restrict__ in_b,
    const float* __restrict__ n1g, const float* __restrict__ n1b,
    float* __restrict__ pl, float* __restrict__ k_all, float* __restrict__ v_all,
    float* __restrict__ q) {
    __shared__ float sm[11264];
    int blk = blockIdx.x;                   // [0,2400)
    int tid = threadIdx.x;
    int w = tid >> 6, lane = tid & 63;

    if (blk < 1800) {
        float* WaS = sm;            // 2220  (30 x 74)
        float* WvS = sm + 2220;     // 1050  (30 x 35)
        float* iwS = sm + 3270;     // 1800  (k,v rows 30..89)
        float* xaR = sm + 5070;     // 4 x 80
        float* xvR = sm + 5390;     // 4 x 40
        float* xn  = sm + 5550;     // 4 x 64
        int po = blk / 300;         // s*LL+l
        int s = po / LL;
        int tb = (blk % 300) * 4 + w;
        int t = tb / BB, b = tb % BB;
        for (int j = tid; j < 2220; j += 256) WaS[j] = Wa[j];
        for (int j = tid; j < 1050; j += 256) WvS[j] = Wv[j];
        const float* iw = in_w + (size_t)po * 2700 + 900;
        for (int j = tid; j < 1800; j += 256) iwS[j] = iw[j];
        const float* xa = x_a + ((size_t)b * TT + t) * 74;
        const float* xv = x_v + ((size_t)b * TT + t) * 35;
        for (int j = lane; j < 74; j += 64) xaR[w * 80 + j] = xa[j];
        if (lane < 35) xvR[w * 40 + lane] = xv[lane];
        __syncthreads();
        float pav = 0.f, pvv = 0.f;
        if (lane < 30) {
            const float* wr = WaS + lane * 74;
            #pragma unroll 2
            for (int j = 0; j < 74; j++) pav += wr[j] * xaR[w * 80 + j];
            const float* wr2 = WvS + lane * 35;
            #pragma unroll 5
            for (int j = 0; j < 35; j++) pvv += wr2[j] * xvR[w * 40 + j];
        }
        const float* g  = n1g + (size_t)po * 30;
        const float* bb = n1b + (size_t)po * 30;
        const float* ib = in_b + (size_t)po * 90;
        float r01[2];
        r01[0] = (s == 0) ? pav : pvv;   // k-source
        r01[1] = (s == 0) ? pvv : pav;   // v-source
        #pragma unroll
        for (int r = 0; r < 2; r++) {
            float xval = (lane < 30) ? r01[r] : 0.f;
            float mean = wsum(xval) * (1.f / 30.f);
            float dv = (lane < 30) ? (xval - mean) : 0.f;
            float var = wsum(dv * dv) * (1.f / 30.f);
            float inv = rsqrtf(var + 1e-5f);
            if (lane < 30) xn[w * 64 + r * 32 + lane] = dv * inv * g[lane] + bb[lane];
        }
        if (lane < 60) {
            int which = lane / 30, dd = lane % 30;
            const float* wr = iwS + lane * 30;
            const float* xr = xn + w * 64 + which * 32;
            float acc = 0.f;
            #pragma unroll 6
            for (int j = 0; j < 30; j++) acc += wr[j] * xr[j];
            acc += ib[30 + lane];
            int i = b * HH + dd / HD, hd = dd % HD;
            float* dst = which ? v_all : k_all;
            dst[((size_t)po * NI + i) * (TT * HD) + t * HD + hd] = acc;
        }
    } else {
        float* WlS = sm;            // 9000 (30 x 300)
        float* iwq = sm + 9000;     // 900  (q rows 0..29)
        float* xlR = sm + 9900;     // 4 x 304
        float* plR = sm + 11116;    // 4 x 32
        int r2 = blk - 1800;        // [0,600)
        int s = r2 / 300;
        int tb = (r2 % 300) * 4 + w;
        int t = tb / BB, b = tb % BB;
        int po = s * LL;            // layer 0
        for (int j = tid; j < 9000; j += 256) WlS[j] = Wl[j];
        const float* iw = in_w + (size_t)po * 2700;
        for (int j = tid; j < 900; j += 256) iwq[j] = iw[j];
        const float* xl = x_l + ((size_t)b * TT + t) * 300;
        for (int j = lane; j < 300; j += 64) xlR[w * 304 + j] = xl[j];
        __syncthreads();
        int d = lane >> 1, jh = lane & 1;
        const float* wr = WlS + (size_t)(d < DD ? d : 0) * 300;
        int j0 = jh ? 150 : 0, j1 = jh ? 300 : 150;
        float acc = 0.f;
        for (int j = j0; j < j1; j++) acc += xlR[w * 304 + j] * wr[j];
        acc += __shfl_xor(acc, 1, 64);
        if (jh == 0 && d < DD) {
            plR[w * 32 + d] = acc;
            pl[tb * 30 + d] = acc;
        }
        float xval = (lane < 30) ? plR[w * 32 + lane] : 0.f;
        float mean = wsum(xval) * (1.f / 30.f);
        float dv = (lane < 30) ? (xval - mean) : 0.f;
        float var = wsum(dv * dv) * (1.f / 30.f);
        float inv = rsqrtf(var + 1e-5f);
        const float* g  = n1g + (size_t)po * 30;
        const float* bb = n1b + (size_t)po * 30;
        const float* ib = in_b + (size_t)po * 90;
        if (lane < 30) xlR[w * 304 + lane] = dv * inv * g[lane] + bb[lane];
        if (lane < 30) {
            const float* wrq = iwq + lane * 30;
            float acc2 = 0.f;
            #pragma unroll 6
            for (int j = 0; j < 30; j++) acc2 += wrq[j] * xlR[w * 304 + j];
            acc2 = (acc2 + ib[lane]) * 0.40824829046386307f;   // HD^-0.5
            int i = b * HH + lane / HD, hd = lane % HD;
            q[((size_t)s * NI + i) * (TT * HD) + t * HD + hd] = acc2;
        }
    }
}

// Score kernel: block = (s, head i, g); stages ONE head f16 in LDS (7.3 KB),
// 4 waves x 2 a's. Fused scores via mfma_f32_32x32x16_f16; vbar row c=150
// provides the mean for free; softmax; attn = sum_b p*q -> global.
// C/D layout: col = lane&31, row = (reg&3) + 8*(reg>>2) + 4*(lane>>5).
__global__ __launch_bounds__(256) void score_kernel(
    const float* __restrict__ q, const float* __restrict__ k_all,
    const float* __restrict__ v_all, int l, float* __restrict__ attn) {
    int blk = blockIdx.x;                   // [0, 1520)
    int s = blk / 760;
    int rem = blk % 760;
    int i = rem / 19;
    int g = rem % 19;
    int tid = threadIdx.x;
    int wv = tid >> 6, lane = tid & 63;
    int lo = lane & 31, hf = lane >> 5;
    int po = s * LL + l;

    __shared__ __align__(16) _Float16 qsh[NR * RSTR];
    __shared__ __align__(16) _Float16 ksh[NR * RSTR];
    __shared__ __align__(16) _Float16 vsh[NR * RSTR];

    const float* qg = q + (size_t)(s * NI + i) * (TT * HD);
    const float* kg = k_all + (size_t)(po * NI + i) * (TT * HD);
    const float* vg = v_all + (size_t)(po * NI + i) * (TT * HD);
    half8 z8;
    #pragma unroll
    for (int t = 0; t < 8; t++) z8[t] = (_Float16)0.f;
    for (int r = tid; r < NR; r += 256) {
        half8 qa = z8, ka = z8, va = z8;
        if (r < TT) {
            #pragma unroll
            for (int t = 0; t < 6; t++) {
                qa[t] = (_Float16)qg[r * 6 + t];
                ka[t] = (_Float16)kg[r * 6 + t];
                va[t] = (_Float16)vg[r * 6 + t];
            }
        }
        *(half8*)&qsh[r * RSTR] = qa;
        *(half8*)&ksh[r * RSTR] = ka;
        *(half8*)&vsh[r * RSTR] = va;
    }
    __syncthreads();
    if (wv == 0) {   // vbar row (pre-scaled by 1/150) into vsh row 150
        float v6[6] = {0.f, 0.f, 0.f, 0.f, 0.f, 0.f};
        for (int c = lane; c < TT; c += 64) {
            #pragma unroll
            for (int t = 0; t < 6; t++) v6[t] += (float)vsh[c * RSTR + t];
        }
        #pragma unroll
        for (int m = 32; m > 0; m >>= 1) {
            #pragma unroll
            for (int t = 0; t < 6; t++) v6[t] += __shfl_xor(v6[t], m, 64);
        }
        if (lane < 6) vsh[TT * RSTR + lane] = (_Float16)(v6[lane] * (1.f / TT));
    }
    __syncthreads();

    f32x16 zacc;
    #pragma unroll
    for (int j = 0; j < 16; j++) zacc[j] = 0.f;

    half8 bfrag[5], vhalf[5];
    #pragma unroll
    for (int nt = 0; nt < 5; nt++) {
        int rr = nt * 32 + lo;
        int rc = rr < 151 ? rr : 151;          // 150 = vbar, 151 = zeros
        half8 kf = *(const half8*)&ksh[rc * RSTR];
        half8 vf = *(const half8*)&vsh[rc * RSTR];
        bfrag[nt] = hf ? z8 : kf;
        vhalf[nt] = hf ? z8 : vf;
    }

    for (int ap = 0; ap < 2; ap++) {
        int a = g * 8 + wv * 2 + ap;
        if (a >= TT) break;
        half8 qav = *(const half8*)&qsh[a * RSTR];
        half8 afrag[5];
        #pragma unroll
        for (int nt = 0; nt < 5; nt++) afrag[nt] = vhalf[nt] * qav;  // v_pk_mul_f16

        float fsc[5];
        #pragma unroll
        for (int nb = 0; nb < 5; nb++) {
            float rm = -INFINITY;
            #pragma unroll
            for (int ma = 0; ma < 4; ma++) {
                f32x16 acc = __builtin_amdgcn_mfma_f32_32x32x16_f16(afrag[ma], bfrag[nb], zacc, 0, 0, 0);
                float m = fmaxf(acc[0], acc[1]);
                #pragma unroll
                for (int j = 2; j < 16; j += 2) m = fmaxf(fmaxf(m, acc[j]), acc[j + 1]);
                rm = fmaxf(rm, m);
            }
            f32x16 a4 = __builtin_amdgcn_mfma_f32_32x32x16_f16(afrag[4], bfrag[nb], zacc, 0, 0, 0);
            // live rows: hf==0 -> regs 0..11 (c<=147); hf==1 -> regs 0..9 (c<=149)
            float m4 = fmaxf(a4[0], a4[1]);
            #pragma unroll
            for (int j = 2; j < 10; j += 2) m4 = fmaxf(fmaxf(m4, a4[j]), a4[j + 1]);
            float ext = (hf == 0) ? fmaxf(a4[10], a4[11]) : -INFINITY;
            rm = fmaxf(rm, fmaxf(m4, ext));
            // mean sits at reg10 of hf==1 lanes (row c==150 = vbar row)
            float om = __shfl_xor(a4[10], 32, 64);
            float mn = hf ? a4[10] : om;
            rm = fmaxf(rm, __shfl_xor(rm, 32, 64));
            int bcol = nb * 32 + lo;
            fsc[nb] = (bcol < TT) ? (mn + rm) : -INFINITY;
        }
        float m = fsc[0];
        #pragma unroll
        for (int nb = 1; nb < 5; nb++) m = fmaxf(m, fsc[nb]);
        #pragma unroll
        for (int msk = 16; msk > 0; msk >>= 1) m = fmaxf(m, __shfl_xor(m, msk, 64));
        float e[5], es = 0.f;
        #pragma unroll
        for (int nb = 0; nb < 5; nb++) { e[nb] = __expf(fsc[nb] - m); es += e[nb]; }
        #pragma unroll
        for (int msk = 16; msk > 0; msk >>= 1) es += __shfl_xor(es, msk, 64);
        float acc6[6] = {0.f, 0.f, 0.f, 0.f, 0.f, 0.f};
        #pragma unroll
        for (int nb = 0; nb < 5; nb++) {
            int bcol = nb * 32 + lo;
            int bi = (bcol < TT) ? bcol : 0;
            float wgt = e[nb];
            half8 qrow = *(const half8*)&qsh[bi * RSTR];
            #pragma unroll
            for (int t = 0; t < 6; t++) acc6[t] += wgt * (float)qrow[t];
        }
        #pragma unroll
        for (int msk = 16; msk > 0; msk >>= 1) {
            #pragma unroll
            for (int t = 0; t < 6; t++) acc6[t] += __shfl_xor(acc6[t], msk, 64);
        }
        if (lane == 0) {
            float inv = 1.f / es;
            int bo = i / HH, ho = i % HH;
            float* dst = attn + (size_t)s * ROWF + a * (BB * DD) + bo * DD + ho * HD;
            #pragma unroll
            for (int t = 0; t < 6; t++) dst[t] = acc6[t] * inv;
        }
    }
}

// FFN for layer l + q-projection for layer l+1 (exact per-row fusion).
// No fences/atomics — the head runs as its own tiny kernel (a device-scope
// release fence per block costs ~54 us on 8-XCD gfx950; a launch slot ~8 us).
__global__ __launch_bounds__(256) void ffnlnq_kernel(
    const float* __restrict__ attn, const float* __restrict__ pl,
    const float* __restrict__ out_w, const float* __restrict__ out_b,
    const float* __restrict__ l1w, const float* __restrict__ l1b,
    const float* __restrict__ l2w, const float* __restrict__ l2b,
    const float* __restrict__ n2g, const float* __restrict__ n2b,
    const float* __restrict__ in_w, const float* __restrict__ in_b,
    const float* __restrict__ n1g, const float* __restrict__ n1b,
    int l, int has_next,
    float* __restrict__ h, float* __restrict__ q) {
    int blk = blockIdx.x;                   // [0,600)
    int s = blk / 300;
    int w = threadIdx.x >> 6, lane = threadIdx.x & 63;
    int tb = (blk % 300) * 4 + w;           // [0,1200)
    int t = tb / BB, b = tb % BB;
    int po = s * LL + l;
    const float* ow = out_w + (size_t)po * 900;
    const float* ob = out_b + (size_t)po * 30;
    const float* w1 = l1w + (size_t)po * 3600;
    const float* b1 = l1b + (size_t)po * 120;
    const float* w2 = l2w + (size_t)po * 3600;
    const float* b2 = l2b + (size_t)po * 30;
    const float* g2 = n2g + (size_t)po * 30;
    const float* bb2 = n2b + (size_t)po * 30;
    __shared__ float owS[900];
    __shared__ float w1T[30 * 128];
    __shared__ float w2S[30 * 121];
    __shared__ float iwqS[900];
    __shared__ float arS[4][30], xnS[4][32], hidS[4][120], xqS[4][30];
    for (int j = threadIdx.x; j < 900; j += 256) owS[j] = ow[j];
    for (int j = threadIdx.x; j < 3600; j += 256) w1T[(j % 30) * 128 + (j / 30)] = w1[j];
    for (int j = threadIdx.x; j < 3600; j += 256) w2S[(j / 120) * 121 + (j % 120)] = w2[j];
    if (has_next) {
        const float* iwq = in_w + (size_t)(po + 1) * 2700;
        for (int j = threadIdx.x; j < 900; j += 256) iwqS[j] = iwq[j];
    }
    __syncthreads();
    float* hrow = h + (size_t)s * ROWF + (size_t)tb * 30;
    const float* res = (l == 0) ? (pl + (size_t)tb * 30) : hrow;
    const float* arow = attn + (size_t)s * ROWF + (size_t)tb * 30;
    if (lane < 30) arS[w][lane] = arow[lane];
    float x1v = 0.f;
    if (lane < 30) {
        const float* wr = owS + lane * 30;
        float acc = 0.f;
        #pragma unroll 6
        for (int j = 0; j < 30; j++) acc += wr[j] * arS[w][j];
        x1v = res[lane] + acc + ob[lane];
    }
    float mean = wsum(x1v) * (1.f / 30.f);
    float dv = (lane < 30) ? (x1v - mean) : 0.f;
    float var = wsum(dv * dv) * (1.f / 30.f);
    float inv = rsqrtf(var + 1e-5f);
    if (lane < 30) xnS[w][lane] = dv * inv * g2[lane] + bb2[lane];
    for (int o = lane; o < 120; o += 64) {
        float acc = 0.f;
        #pragma unroll 6
        for (int j = 0; j < 30; j++) acc += w1T[j * 128 + o] * xnS[w][j];
        hidS[w][o] = fmaxf(acc + b1[o], 0.f);
    }
    float newh = 0.f;
    if (lane < 30) {
        const float* wr = w2S + lane * 121;
        float acc = 0.f;
        #pragma unroll 8
        for (int j = 0; j < 120; j++) acc += wr[j] * hidS[w][j];
        newh = x1v + acc + b2[lane];
        hrow[lane] = newh;
    }
    if (has_next) {
        const float* g1 = n1g + (size_t)(po + 1) * 30;
        const float* bb1 = n1b + (size_t)(po + 1) * 30;
        const float* ibq = in_b + (size_t)(po + 1) * 90;
        float mean2 = wsum(newh) * (1.f / 30.f);
        float dv2 = (lane < 30) ? (newh - mean2) : 0.f;
        float var2 = wsum(dv2 * dv2) * (1.f / 30.f);
        float inv2 = rsqrtf(var2 + 1e-5f);
        if (lane < 30) xqS[w][lane] = dv2 * inv2 * g1[lane] + bb1[lane];
        if (lane < 30) {
            const float* wr = iwqS + lane * 30;
            float acc = 0.f;
            #pragma unroll 6
            for (int j = 0; j < 30; j++) acc += wr[j] * xqS[w][j];
            acc = (acc + ibq[lane]) * 0.40824829046386307f;
            int i = b * HH + lane / HD, hd = lane % HD;
            q[((size_t)s * NI + i) * (TT * HD) + t * HD + hd] = acc;
        }
    }
}

// Final head: last_hs, proj MLP + residual, scalar out. Writes all 488 outputs.
__global__ __launch_bounds__(256) void head_kernel(
    const float* __restrict__ h,
    const float* __restrict__ p1w, const float* __restrict__ p1b,
    const float* __restrict__ p2w, const float* __restrict__ p2b,
    const float* __restrict__ ow, const float* __restrict__ ob,
    float* __restrict__ out) {
    int tid = threadIdx.x;
    __shared__ float lh[480], hid[480], pr[480];
    for (int idx = tid; idx < 480; idx += 256) {
        int b = idx / 60, j = idx % 60;
        int s = j / 30, d = j % 30;
        float vv = h[(size_t)s * ROWF + 149 * (BB * DD) + b * DD + d];
        lh[idx] = vv;
        out[8 + idx] = vv;   // last_hs
    }
    __syncthreads();
    for (int idx = tid; idx < 480; idx += 256) {
        int b = idx / 60, o = idx % 60;
        const float* wr = p1w + o * 60;
        float acc = p1b[o];
        for (int j = 0; j < 60; j++) acc += wr[j] * lh[b * 60 + j];
        hid[idx] = fmaxf(acc, 0.f);
    }
    __syncthreads();
    for (int idx = tid; idx < 480; idx += 256) {
        int b = idx / 60, d = idx % 60;
        const float* wr = p2w + d * 60;
        float acc = p2b[d];
        for (int j = 0; j < 60; j++) acc += wr[j] * hid[b * 60 + j];
        pr[idx] = acc + lh[idx];
    }
    __syncthreads();
    if (tid < 8) {
        float acc = ob[0];
        for (int j = 0; j < 60; j++) acc += pr[tid * 60 + j] * ow[j];
        out[tid] = acc;      // out
    }
}

extern "C" void kernel_launch(void* const* d_in, const int* in_sizes, int n_in,
                              void* d_out, int out_size, void* d_ws, size_t ws_size,
                              hipStream_t stream) {
    const float* x_l   = (const float*)d_in[0];
    const float* x_a   = (const float*)d_in[1];
    const float* x_v   = (const float*)d_in[2];
    const float* Wl    = (const float*)d_in[3];
    const float* Wa    = (const float*)d_in[4];
    const float* Wv    = (const float*)d_in[5];
    const float* in_w  = (const float*)d_in[6];
    const float* in_b  = (const float*)d_in[7];
    const float* out_w = (const float*)d_in[8];
    const float* out_b = (const float*)d_in[9];
    const float* l1w   = (const float*)d_in[10];
    const float* l1b   = (const float*)d_in[11];
    const float* l2w   = (const float*)d_in[12];
    const float* l2b   = (const float*)d_in[13];
    const float* n1g   = (const float*)d_in[14];
    const float* n1b   = (const float*)d_in[15];
    const float* n2g   = (const float*)d_in[16];
    const float* n2b   = (const float*)d_in[17];
    const float* p1w   = (const float*)d_in[18];
    const float* p1b   = (const float*)d_in[19];
    const float* p2w   = (const float*)d_in[20];
    const float* p2b   = (const float*)d_in[21];
    const float* oww   = (const float*)d_in[22];
    const float* obb   = (const float*)d_in[23];

    float* ws = (float*)d_ws;
    float* pl    = ws;             // 36000
    float* h     = ws + 108000;    // 72000  [2][T][B][D]
    float* q     = ws + 180000;    // 72000  [2][NI][TT][HD]
    float* k_all = ws + 252000;    // 216000 [6][NI][TT][HD]
    float* v_all = ws + 468000;    // 216000
    float* at    = ws + 684000;    // 72000

    fused_pre_kernel<<<2400, 256, 0, stream>>>(x_l, x_a, x_v, Wl, Wa, Wv,
                                               in_w, in_b, n1g, n1b,
                                               pl, k_all, v_all, q);
    for (int l = 0; l < LL; l++) {
        score_kernel<<<1520, 256, 0, stream>>>(q, k_all, v_all, l, at);
        ffnlnq_kernel<<<600, 256, 0, stream>>>(at, pl, out_w, out_b, l1w, l1b, l2w, l2b,
                                               n2g, n2b, in_w, in_b, n1g, n1b,
                                               l, (l < LL - 1) ? 1 : 0, h, q);
    }
    head_kernel<<<1, 256, 0, stream>>>(h, p1w, p1b, p2w, p2b, oww, obb, (float*)d_out);
}

// Round 12
// 242.810 us; speedup vs baseline: 1.2381x; 1.0865x over previous
//
#include <hip/hip_runtime.h>
#include <math.h>

// Model dims
#define BB 8
#define TT 150
#define DD 30
#define HH 5
#define HD 6
#define LL 3
#define NI 40            // B*H heads per stream
#define ROWF (TT*BB*DD)  // 36000 floats per [T,B,D] buffer
#define RSTR 8           // padded LDS row stride in halves (16B -> ds_read_b128)
#define NR 152           // padded row count (150 data + vbar + zero)

typedef _Float16 half8 __attribute__((ext_vector_type(8)));
typedef float f32x16 __attribute__((ext_vector_type(16)));

__device__ __forceinline__ float wsum(float v) {
    #pragma unroll
    for (int m = 32; m > 0; m >>= 1) v += __shfl_xor(v, m, 64);
    return v;
}

// All three k=1 conv projections. 300 blocks per input; weights staged in LDS.
__global__ __launch_bounds__(256) void proj3_kernel(
    const float* __restrict__ x_l, const float* __restrict__ x_a, const float* __restrict__ x_v,
    const float* __restrict__ Wl, const float* __restrict__ Wa, const float* __restrict__ Wv,
    float* __restrict__ pl, float* __restrict__ pa, float* __restrict__ pv) {
    int blk = blockIdx.x;                   // [0,900)
    int which = blk / 300;
    int w = threadIdx.x >> 6, lane = threadIdx.x & 63;
    int rowu = (blk % 300) * 4 + w;         // [0,1200)
    int t = rowu / BB, b = rowu % BB;
    const float* x = which == 0 ? x_l : (which == 1 ? x_a : x_v);
    const float* W = which == 0 ? Wl : (which == 1 ? Wa : Wv);
    float* out = which == 0 ? pl : (which == 1 ? pa : pv);
    int Cin = which == 0 ? 300 : (which == 1 ? 74 : 35);
    int cst = Cin | 1;                      // odd LDS row stride -> bank spread
    __shared__ float WS[30 * 301];
    __shared__ float xr[4][304];
    for (int j = threadIdx.x; j < DD * Cin; j += 256)
        WS[(j / Cin) * cst + (j % Cin)] = W[j];
    const float* xp = x + ((size_t)b * TT + t) * Cin;
    for (int j = lane; j < Cin; j += 64) xr[w][j] = xp[j];
    __syncthreads();
    int d = lane >> 1, jh = lane & 1;
    int h1 = Cin >> 1;
    int j0 = jh ? h1 : 0, j1 = jh ? Cin : h1;
    const float* wr = WS + (size_t)(d < DD ? d : 0) * cst;
    float acc = 0.f;
    for (int j = j0; j < j1; j++) acc += xr[w][j] * wr[j];
    acc += __shfl_xor(acc, 1, 64);
    if (jh == 0 && d < DD) out[t * (BB * DD) + b * DD + d] = acc;
}

// Merged: blocks [0,1800) compute k,v for all 6 (s,l); blocks [1800,2400) q for layer 0.
__global__ __launch_bounds__(256) void kvq0_kernel(
    const float* __restrict__ pl, const float* __restrict__ pa, const float* __restrict__ pv,
    const float* __restrict__ in_w, const float* __restrict__ in_b,
    const float* __restrict__ n1g, const float* __restrict__ n1b,
    float* __restrict__ k_all, float* __restrict__ v_all, float* __restrict__ q) {
    int blk = blockIdx.x;                   // [0,2400)
    int w = threadIdx.x >> 6, lane = threadIdx.x & 63;
    __shared__ float iwS[1800];
    __shared__ float xn[4][2][30];
    if (blk < 1800) {
        int po = blk / 300;                 // s*LL+l
        int s = po / LL;
        int tb = (blk % 300) * 4 + w;       // [0,1200)
        int t = tb / BB, b = tb % BB;
        const float* xk = (s == 0) ? pa : pv;
        const float* xv = (s == 0) ? pv : pa;
        const float* iw = in_w + (size_t)po * 2700 + 900;   // k,v rows 30..89
        const float* ib = in_b + (size_t)po * 90;
        const float* g  = n1g + (size_t)po * 30;
        const float* bb = n1b + (size_t)po * 30;
        for (int j = threadIdx.x; j < 1800; j += 256) iwS[j] = iw[j];
        const float* rows[2] = { xk + (size_t)tb * 30, xv + (size_t)tb * 30 };
        for (int r = 0; r < 2; r++) {
            float xval = (lane < 30) ? rows[r][lane] : 0.f;
            float mean = wsum(xval) * (1.f / 30.f);
            float dv = (lane < 30) ? (xval - mean) : 0.f;
            float var = wsum(dv * dv) * (1.f / 30.f);
            float inv = rsqrtf(var + 1e-5f);
            if (lane < 30) xn[w][r][lane] = dv * inv * g[lane] + bb[lane];
        }
        __syncthreads();
        if (lane < 60) {
            int which = lane / 30, dd = lane % 30;
            const float* wr = iwS + lane * 30;
            const float* xv2 = xn[w][which];
            float acc = 0.f;
            #pragma unroll 6
            for (int j = 0; j < 30; j++) acc += wr[j] * xv2[j];
            acc += ib[30 + lane];
            int i = b * HH + dd / HD, hd = dd % HD;
            float* dst = which ? v_all : k_all;
            dst[((size_t)po * NI + i) * (TT * HD) + t * HD + hd] = acc;
        }
    } else {
        int r2 = blk - 1800;                // [0,600)
        int s = r2 / 300;
        int tb = (r2 % 300) * 4 + w;
        int t = tb / BB, b = tb % BB;
        int po = s * LL;                    // layer 0
        const float* iw = in_w + (size_t)po * 2700;   // q rows 0..29
        const float* ib = in_b + (size_t)po * 90;
        const float* g  = n1g + (size_t)po * 30;
        const float* bb = n1b + (size_t)po * 30;
        for (int j = threadIdx.x; j < 900; j += 256) iwS[j] = iw[j];
        const float* row = pl + (size_t)tb * 30;
        float xval = (lane < 30) ? row[lane] : 0.f;
        float mean = wsum(xval) * (1.f / 30.f);
        float dv = (lane < 30) ? (xval - mean) : 0.f;
        float var = wsum(dv * dv) * (1.f / 30.f);
        float inv = rsqrtf(var + 1e-5f);
        if (lane < 30) xn[w][0][lane] = dv * inv * g[lane] + bb[lane];
        __syncthreads();
        if (lane < 30) {
            const float* wr = iwS + lane * 30;
            float acc = 0.f;
            #pragma unroll 6
            for (int j = 0; j < 30; j++) acc += wr[j] * xn[w][0][j];
            acc = (acc + ib[lane]) * 0.40824829046386307f;   // HD^-0.5
            int i = b * HH + lane / HD, hd = lane % HD;
            q[((size_t)s * NI + i) * (TT * HD) + t * HD + hd] = acc;
        }
    }
}

// Score kernel: block = (s, head i, g); stages ONE head f16 in LDS (7.3 KB),
// 4 waves x 2 a's. Fused scores via mfma_f32_32x32x16_f16; vbar row c=150
// provides the mean for free; softmax; attn = sum_b p*q -> global.
// C/D layout: col = lane&31, row = (reg&3) + 8*(reg>>2) + 4*(lane>>5).
__global__ __launch_bounds__(256) void score_kernel(
    const float* __restrict__ q, const float* __restrict__ k_all,
    const float* __restrict__ v_all, int l, float* __restrict__ attn) {
    int blk = blockIdx.x;                   // [0, 1520)
    int s = blk / 760;
    int rem = blk % 760;
    int i = rem / 19;
    int g = rem % 19;
    int tid = threadIdx.x;
    int wv = tid >> 6, lane = tid & 63;
    int lo = lane & 31, hf = lane >> 5;
    int po = s * LL + l;

    __shared__ __align__(16) _Float16 qsh[NR * RSTR];
    __shared__ __align__(16) _Float16 ksh[NR * RSTR];
    __shared__ __align__(16) _Float16 vsh[NR * RSTR];

    const float* qg = q + (size_t)(s * NI + i) * (TT * HD);
    const float* kg = k_all + (size_t)(po * NI + i) * (TT * HD);
    const float* vg = v_all + (size_t)(po * NI + i) * (TT * HD);
    // one padded half8 row per thread (rows 150/151 zeroed; vbar fills 150 later)
    half8 z8;
    #pragma unroll
    for (int t = 0; t < 8; t++) z8[t] = (_Float16)0.f;
    for (int r = tid; r < NR; r += 256) {
        half8 qa = z8, ka = z8, va = z8;
        if (r < TT) {
            #pragma unroll
            for (int t = 0; t < 6; t++) {
                qa[t] = (_Float16)qg[r * 6 + t];
                ka[t] = (_Float16)kg[r * 6 + t];
                va[t] = (_Float16)vg[r * 6 + t];
            }
        }
        *(half8*)&qsh[r * RSTR] = qa;
        *(half8*)&ksh[r * RSTR] = ka;
        *(half8*)&vsh[r * RSTR] = va;
    }
    __syncthreads();
    if (wv == 0) {   // vbar row (pre-scaled by 1/150) into vsh row 150
        float v6[6] = {0.f, 0.f, 0.f, 0.f, 0.f, 0.f};
        for (int c = lane; c < TT; c += 64) {
            #pragma unroll
            for (int t = 0; t < 6; t++) v6[t] += (float)vsh[c * RSTR + t];
        }
        #pragma unroll
        for (int m = 32; m > 0; m >>= 1) {
            #pragma unroll
            for (int t = 0; t < 6; t++) v6[t] += __shfl_xor(v6[t], m, 64);
        }
        if (lane < 6) vsh[TT * RSTR + lane] = (_Float16)(v6[lane] * (1.f / TT));
    }
    __syncthreads();

    f32x16 zacc;
    #pragma unroll
    for (int j = 0; j < 16; j++) zacc[j] = 0.f;

    half8 bfrag[5], vhalf[5];
    #pragma unroll
    for (int nt = 0; nt < 5; nt++) {
        int rr = nt * 32 + lo;
        int rc = rr < 151 ? rr : 151;          // 150 = vbar, 151 = zeros
        half8 kf = *(const half8*)&ksh[rc * RSTR];
        half8 vf = *(const half8*)&vsh[rc * RSTR];
        bfrag[nt] = hf ? z8 : kf;
        vhalf[nt] = hf ? z8 : vf;
    }

    for (int ap = 0; ap < 2; ap++) {
        int a = g * 8 + wv * 2 + ap;
        if (a >= TT) break;
        half8 qav = *(const half8*)&qsh[a * RSTR];
        half8 afrag[5];
        #pragma unroll
        for (int nt = 0; nt < 5; nt++) afrag[nt] = vhalf[nt] * qav;  // v_pk_mul_f16

        float fsc[5];
        #pragma unroll
        for (int nb = 0; nb < 5; nb++) {
            float rm = -INFINITY;
            #pragma unroll
            for (int ma = 0; ma < 4; ma++) {
                f32x16 acc = __builtin_amdgcn_mfma_f32_32x32x16_f16(afrag[ma], bfrag[nb], zacc, 0, 0, 0);
                float m = fmaxf(acc[0], acc[1]);
                #pragma unroll
                for (int j = 2; j < 16; j += 2) m = fmaxf(fmaxf(m, acc[j]), acc[j + 1]);
                rm = fmaxf(rm, m);
            }
            f32x16 a4 = __builtin_amdgcn_mfma_f32_32x32x16_f16(afrag[4], bfrag[nb], zacc, 0, 0, 0);
            // live rows: hf==0 -> regs 0..11 (c<=147); hf==1 -> regs 0..9 (c<=149)
            float m4 = fmaxf(a4[0], a4[1]);
            #pragma unroll
            for (int j = 2; j < 10; j += 2) m4 = fmaxf(fmaxf(m4, a4[j]), a4[j + 1]);
            float ext = (hf == 0) ? fmaxf(a4[10], a4[11]) : -INFINITY;
            rm = fmaxf(rm, fmaxf(m4, ext));
            // mean sits at reg10 of hf==1 lanes (row c==150 = vbar row)
            float om = __shfl_xor(a4[10], 32, 64);
            float mn = hf ? a4[10] : om;
            rm = fmaxf(rm, __shfl_xor(rm, 32, 64));
            int bcol = nb * 32 + lo;
            fsc[nb] = (bcol < TT) ? (mn + rm) : -INFINITY;
        }
        float m = fsc[0];
        #pragma unroll
        for (int nb = 1; nb < 5; nb++) m = fmaxf(m, fsc[nb]);
        #pragma unroll
        for (int msk = 16; msk > 0; msk >>= 1) m = fmaxf(m, __shfl_xor(m, msk, 64));
        float e[5], es = 0.f;
        #pragma unroll
        for (int nb = 0; nb < 5; nb++) { e[nb] = __expf(fsc[nb] - m); es += e[nb]; }
        #pragma unroll
        for (int msk = 16; msk > 0; msk >>= 1) es += __shfl_xor(es, msk, 64);
        float acc6[6] = {0.f, 0.f, 0.f, 0.f, 0.f, 0.f};
        #pragma unroll
        for (int nb = 0; nb < 5; nb++) {
            int bcol = nb * 32 + lo;
            int bi = (bcol < TT) ? bcol : 0;
            float wgt = e[nb];
            half8 qrow = *(const half8*)&qsh[bi * RSTR];
            #pragma unroll
            for (int t = 0; t < 6; t++) acc6[t] += wgt * (float)qrow[t];
        }
        #pragma unroll
        for (int msk = 16; msk > 0; msk >>= 1) {
            #pragma unroll
            for (int t = 0; t < 6; t++) acc6[t] += __shfl_xor(acc6[t], msk, 64);
        }
        if (lane == 0) {
            float inv = 1.f / es;
            int bo = i / HH, ho = i % HH;
            float* dst = attn + (size_t)s * ROWF + a * (BB * DD) + bo * DD + ho * HD;
            #pragma unroll
            for (int t = 0; t < 6; t++) dst[t] = acc6[t] * inv;
        }
    }
}

// FFN for layer l + q-projection for layer l+1 (exact per-row fusion).
__global__ __launch_bounds__(256) void ffnlnq_kernel(
    const float* __restrict__ attn, const float* __restrict__ pl,
    const float* __restrict__ out_w, const float* __restrict__ out_b,
    const float* __restrict__ l1w, const float* __restrict__ l1b,
    const float* __restrict__ l2w, const float* __restrict__ l2b,
    const float* __restrict__ n2g, const float* __restrict__ n2b,
    const float* __restrict__ in_w, const float* __restrict__ in_b,
    const float* __restrict__ n1g, const float* __restrict__ n1b,
    int l, int has_next,
    float* __restrict__ h, float* __restrict__ q) {
    int blk = blockIdx.x;                   // [0,600)
    int s = blk / 300;
    int w = threadIdx.x >> 6, lane = threadIdx.x & 63;
    int tb = (blk % 300) * 4 + w;           // [0,1200)
    int t = tb / BB, b = tb % BB;
    int po = s * LL + l;
    const float* ow = out_w + (size_t)po * 900;
    const float* ob = out_b + (size_t)po * 30;
    const float* w1 = l1w + (size_t)po * 3600;
    const float* b1 = l1b + (size_t)po * 120;
    const float* w2 = l2w + (size_t)po * 3600;
    const float* b2 = l2b + (size_t)po * 30;
    const float* g2 = n2g + (size_t)po * 30;
    const float* bb2 = n2b + (size_t)po * 30;
    __shared__ float owS[900];
    __shared__ float w1T[30 * 128];
    __shared__ float w2S[30 * 121];
    __shared__ float iwqS[900];
    __shared__ float arS[4][30], xnS[4][32], hidS[4][120], xqS[4][30];
    for (int j = threadIdx.x; j < 900; j += 256) owS[j] = ow[j];
    for (int j = threadIdx.x; j < 3600; j += 256) w1T[(j % 30) * 128 + (j / 30)] = w1[j];
    for (int j = threadIdx.x; j < 3600; j += 256) w2S[(j / 120) * 121 + (j % 120)] = w2[j];
    if (has_next) {
        const float* iwq = in_w + (size_t)(po + 1) * 2700;
        for (int j = threadIdx.x; j < 900; j += 256) iwqS[j] = iwq[j];
    }
    __syncthreads();
    float* hrow = h + (size_t)s * ROWF + (size_t)tb * 30;
    const float* res = (l == 0) ? (pl + (size_t)tb * 30) : hrow;
    const float* arow = attn + (size_t)s * ROWF + (size_t)tb * 30;
    if (lane < 30) arS[w][lane] = arow[lane];
    float x1v = 0.f;
    if (lane < 30) {
        const float* wr = owS + lane * 30;
        float acc = 0.f;
        #pragma unroll 6
        for (int j = 0; j < 30; j++) acc += wr[j] * arS[w][j];
        x1v = res[lane] + acc + ob[lane];
    }
    float mean = wsum(x1v) * (1.f / 30.f);
    float dv = (lane < 30) ? (x1v - mean) : 0.f;
    float var = wsum(dv * dv) * (1.f / 30.f);
    float inv = rsqrtf(var + 1e-5f);
    if (lane < 30) xnS[w][lane] = dv * inv * g2[lane] + bb2[lane];
    for (int o = lane; o < 120; o += 64) {
        float acc = 0.f;
        #pragma unroll 6
        for (int j = 0; j < 30; j++) acc += w1T[j * 128 + o] * xnS[w][j];
        hidS[w][o] = fmaxf(acc + b1[o], 0.f);
    }
    float newh = 0.f;
    if (lane < 30) {
        const float* wr = w2S + lane * 121;
        float acc = 0.f;
        #pragma unroll 8
        for (int j = 0; j < 120; j++) acc += wr[j] * hidS[w][j];
        newh = x1v + acc + b2[lane];
        hrow[lane] = newh;
    }
    if (has_next) {
        const float* g1 = n1g + (size_t)(po + 1) * 30;
        const float* bb1 = n1b + (size_t)(po + 1) * 30;
        const float* ibq = in_b + (size_t)(po + 1) * 90;
        float mean2 = wsum(newh) * (1.f / 30.f);
        float dv2 = (lane < 30) ? (newh - mean2) : 0.f;
        float var2 = wsum(dv2 * dv2) * (1.f / 30.f);
        float inv2 = rsqrtf(var2 + 1e-5f);
        if (lane < 30) xqS[w][lane] = dv2 * inv2 * g1[lane] + bb1[lane];
        if (lane < 30) {
            const float* wr = iwqS + lane * 30;
            float acc = 0.f;
            #pragma unroll 6
            for (int j = 0; j < 30; j++) acc += wr[j] * xqS[w][j];
            acc = (acc + ibq[lane]) * 0.40824829046386307f;
            int i = b * HH + lane / HD, hd = lane % HD;
            q[((size_t)s * NI + i) * (TT * HD) + t * HD + hd] = acc;
        }
    }
}

// Final head: last_hs, proj MLP + residual, scalar out. Writes all 488 outputs.
__global__ __launch_bounds__(256) void head_kernel(
    const float* __restrict__ h,
    const float* __restrict__ p1w, const float* __restrict__ p1b,
    const float* __restrict__ p2w, const float* __restrict__ p2b,
    const float* __restrict__ ow, const float* __restrict__ ob,
    float* __restrict__ out) {
    int tid = threadIdx.x;
    __shared__ float lh[480], hid[480], pr[480];
    for (int idx = tid; idx < 480; idx += 256) {
        int b = idx / 60, j = idx % 60;
        int s = j / 30, d = j % 30;
        float vv = h[(size_t)s * ROWF + 149 * (BB * DD) + b * DD + d];
        lh[idx] = vv;
        out[8 + idx] = vv;   // last_hs
    }
    __syncthreads();
    for (int idx = tid; idx < 480; idx += 256) {
        int b = idx / 60, o = idx % 60;
        const float* wr = p1w + o * 60;
        float acc = p1b[o];
        for (int j = 0; j < 60; j++) acc += wr[j] * lh[b * 60 + j];
        hid[idx] = fmaxf(acc, 0.f);
    }
    __syncthreads();
    for (int idx = tid; idx < 480; idx += 256) {
        int b = idx / 60, d = idx % 60;
        const float* wr = p2w + d * 60;
        float acc = p2b[d];
        for (int j = 0; j < 60; j++) acc += wr[j] * hid[b * 60 + j];
        pr[idx] = acc + lh[idx];
    }
    __syncthreads();
    if (tid < 8) {
        float acc = ob[0];
        for (int j = 0; j < 60; j++) acc += pr[tid * 60 + j] * ow[j];
        out[tid] = acc;      // out
    }
}

extern "C" void kernel_launch(void* const* d_in, const int* in_sizes, int n_in,
                              void* d_out, int out_size, void* d_ws, size_t ws_size,
                              hipStream_t stream) {
    const float* x_l   = (const float*)d_in[0];
    const float* x_a   = (const float*)d_in[1];
    const float* x_v   = (const float*)d_in[2];
    const float* Wl    = (const float*)d_in[3];
    const float* Wa    = (const float*)d_in[4];
    const float* Wv    = (const float*)d_in[5];
    const float* in_w  = (const float*)d_in[6];
    const float* in_b  = (const float*)d_in[7];
    const float* out_w = (const float*)d_in[8];
    const float* out_b = (const float*)d_in[9];
    const float* l1w   = (const float*)d_in[10];
    const float* l1b   = (const float*)d_in[11];
    const float* l2w   = (const float*)d_in[12];
    const float* l2b   = (const float*)d_in[13];
    const float* n1g   = (const float*)d_in[14];
    const float* n1b   = (const float*)d_in[15];
    const float* n2g   = (const float*)d_in[16];
    const float* n2b   = (const float*)d_in[17];
    const float* p1w   = (const float*)d_in[18];
    const float* p1b   = (const float*)d_in[19];
    const float* p2w   = (const float*)d_in[20];
    const float* p2b   = (const float*)d_in[21];
    const float* oww   = (const float*)d_in[22];
    const float* obb   = (const float*)d_in[23];

    float* ws = (float*)d_ws;
    float* pl    = ws;             // 36000
    float* pa    = ws + 36000;     // 36000
    float* pv    = ws + 72000;     // 36000
    float* h     = ws + 108000;    // 72000  [2][T][B][D]
    float* q     = ws + 180000;    // 72000  [2][NI][TT][HD]
    float* k_all = ws + 252000;    // 216000 [6][NI][TT][HD]
    float* v_all = ws + 468000;    // 216000
    float* at    = ws + 684000;    // 72000

    proj3_kernel<<<900, 256, 0, stream>>>(x_l, x_a, x_v, Wl, Wa, Wv, pl, pa, pv);
    kvq0_kernel<<<2400, 256, 0, stream>>>(pl, pa, pv, in_w, in_b, n1g, n1b,
                                          k_all, v_all, q);
    for (int l = 0; l < LL; l++) {
        score_kernel<<<1520, 256, 0, stream>>>(q, k_all, v_all, l, at);
        ffnlnq_kernel<<<600, 256, 0, stream>>>(at, pl, out_w, out_b, l1w, l1b, l2w, l2b,
                                               n2g, n2b, in_w, in_b, n1g, n1b,
                                               l, (l < LL - 1) ? 1 : 0, h, q);
    }
    head_kernel<<<1, 256, 0, stream>>>(h, p1w, p1b, p2w, p2b, oww, obb, (float*)d_out);
}